// Round 1
// baseline (484.865 us; speedup 1.0000x reference)
//
#include <hip/hip_runtime.h>
#include <hip/hip_bf16.h>

// ---------------------------------------------------------------------------
// Fused GQA attention block: out = dense( attn( x*Wq, x*Wkv ) )
// B=2, SQ=2048, HIDDEN=2048, HEADS=16, GROUPS=4, KVC=128, causal, scale=1/sqrt(128)
// Strategy: bf16 MFMA for all GEMM-shaped compute, fp32 accumulate.
// ---------------------------------------------------------------------------

typedef __attribute__((ext_vector_type(4))) float f32x4;
typedef __attribute__((ext_vector_type(8))) short bf16x8;
typedef __attribute__((ext_vector_type(4))) short bf16x4;

__device__ __forceinline__ unsigned short f2bf(float f) {
    unsigned u = __builtin_bit_cast(unsigned, f);
    unsigned r = u + 0x7fffu + ((u >> 16) & 1u);   // round-to-nearest-even
    return (unsigned short)(r >> 16);
}

// ---------------------------------------------------------------------------
// GEMM: C(MxN) = A(MxK) * B(KxN).  A row-major (fp32 or bf16), B row-major fp32.
// 128x128 tile, BK=32, 256 threads (4 waves, 2x2), each wave 64x64 via 4x4
// mfma_f32_16x16x32_bf16 fragments.  B is staged TRANSPOSED into LDS so both
// fragment reads are contiguous ds_read_b128.  +8 bf16 padding (stride 40).
// ---------------------------------------------------------------------------
template<bool A_BF16, bool C_BF16>
__global__ __launch_bounds__(256)
void gemm_kernel(const void* __restrict__ Av, const float* __restrict__ B,
                 void* __restrict__ Cv, int M, int N, int K)
{
    __shared__ unsigned short Alds[128][40];   // [m][k]
    __shared__ unsigned short Blds[128][40];   // [n][k] (transposed)

    const int tid = threadIdx.x;
    const int lane = tid & 63;
    const int wid = tid >> 6;
    const int wr = wid >> 1, wc = wid & 1;
    const int m0 = blockIdx.y * 128;
    const int n0 = blockIdx.x * 128;
    const int l16 = lane & 15, lg = lane >> 4;

    f32x4 acc[4][4];
#pragma unroll
    for (int m = 0; m < 4; ++m)
#pragma unroll
        for (int n = 0; n < 4; ++n) acc[m][n] = (f32x4){0.f, 0.f, 0.f, 0.f};

    for (int kt = 0; kt < K; kt += 32) {
        // ---- stage A tile (128 x 32) ----
        if constexpr (A_BF16) {
            const unsigned short* A = (const unsigned short*)Av;
#pragma unroll
            for (int i = 0; i < 2; ++i) {
                int f = tid + i * 256;          // 512 chunks of 8 bf16
                int row = f >> 2;
                int c8 = (f & 3) * 8;
                bf16x8 v = *reinterpret_cast<const bf16x8*>(
                    &A[(size_t)(m0 + row) * K + kt + c8]);
                *reinterpret_cast<bf16x8*>(&Alds[row][c8]) = v;
            }
        } else {
            const float* A = (const float*)Av;
#pragma unroll
            for (int i = 0; i < 4; ++i) {
                int f = tid + i * 256;          // 1024 chunks of 4 fp32
                int row = f >> 3;
                int c4 = (f & 7) * 4;
                float4 v = *reinterpret_cast<const float4*>(
                    &A[(size_t)(m0 + row) * K + kt + c4]);
                bf16x4 pk = { (short)f2bf(v.x), (short)f2bf(v.y),
                              (short)f2bf(v.z), (short)f2bf(v.w) };
                *reinterpret_cast<bf16x4*>(&Alds[row][c4]) = pk;
            }
        }
        // ---- stage B tile transposed: Blds[n][k] (k-strip per thread) ----
        {
            int nn = tid & 127;
            int hb = tid >> 7;
#pragma unroll
            for (int i = 0; i < 4; ++i) {
                int ks = hb * 4 + i * 8;
                float v0 = B[(size_t)(kt + ks + 0) * N + n0 + nn];
                float v1 = B[(size_t)(kt + ks + 1) * N + n0 + nn];
                float v2 = B[(size_t)(kt + ks + 2) * N + n0 + nn];
                float v3 = B[(size_t)(kt + ks + 3) * N + n0 + nn];
                bf16x4 pk = { (short)f2bf(v0), (short)f2bf(v1),
                              (short)f2bf(v2), (short)f2bf(v3) };
                *reinterpret_cast<bf16x4*>(&Blds[nn][ks]) = pk;
            }
        }
        __syncthreads();

        bf16x8 afrag[4], bfrag[4];
#pragma unroll
        for (int m = 0; m < 4; ++m)
            afrag[m] = *reinterpret_cast<const bf16x8*>(
                &Alds[wr * 64 + m * 16 + l16][lg * 8]);
#pragma unroll
        for (int n = 0; n < 4; ++n)
            bfrag[n] = *reinterpret_cast<const bf16x8*>(
                &Blds[wc * 64 + n * 16 + l16][lg * 8]);
#pragma unroll
        for (int m = 0; m < 4; ++m)
#pragma unroll
            for (int n = 0; n < 4; ++n)
                acc[m][n] = __builtin_amdgcn_mfma_f32_16x16x32_bf16(
                    afrag[m], bfrag[n], acc[m][n], 0, 0, 0);
        __syncthreads();
    }

    // ---- epilogue: C/D layout col = lane&15, row = (lane>>4)*4 + reg ----
#pragma unroll
    for (int m = 0; m < 4; ++m) {
#pragma unroll
        for (int n = 0; n < 4; ++n) {
#pragma unroll
            for (int r = 0; r < 4; ++r) {
                int row = m0 + wr * 64 + m * 16 + lg * 4 + r;
                int col = n0 + wc * 64 + n * 16 + l16;
                float val = acc[m][n][r];
                if constexpr (C_BF16)
                    ((unsigned short*)Cv)[(size_t)row * N + col] = f2bf(val);
                else
                    ((float*)Cv)[(size_t)row * N + col] = val;
            }
        }
    }
}

// ---------------------------------------------------------------------------
// Flash attention, causal, GQA (4 Q-heads share one KV group).
// Block = 256 threads (4 waves).  Block handles 64 Q rows of one (batch,head);
// each wave owns 16 rows.  KBLK=32 keys per tile.  Q hoisted to registers.
// K in LDS row-major [k][d] (+8 pad), V in LDS transposed [d][k] (+8 pad).
// Online softmax state per (lane-group,reg) row, wave-parallel shfl reduce.
// ---------------------------------------------------------------------------
__global__ __launch_bounds__(256)
void attn_kernel(const unsigned short* __restrict__ Q,   // (B*SQ) x 2048 bf16
                 const unsigned short* __restrict__ KV,  // (B*SQ) x 1024 bf16
                 unsigned short* __restrict__ CTX,       // (B*SQ) x 2048 bf16
                 int SQ)
{
    __shared__ unsigned short Klds[32][136];      // [k][d]
    __shared__ unsigned short Vlds[128][40];      // [d][k]
    __shared__ unsigned short Plds[4][16][40];    // per-wave P tile [q][k]

    const int tid = threadIdx.x;
    const int lane = tid & 63;
    const int w = tid >> 6;
    const int l16 = lane & 15, lg = lane >> 4;
    const int qt = blockIdx.x;
    const int hh = blockIdx.y;
    const int b  = blockIdx.z;
    const int g  = hh >> 2;                        // KV group

    const size_t qbase  = (size_t)b * SQ * 2048;
    const size_t kvbase = (size_t)b * SQ * 1024;

    // hoist Q fragments: wave rows qt*64 + w*16 + l16, 4 k-steps over D=128
    const int qrow_l = qt * 64 + w * 16 + l16;
    bf16x8 qfrag[4];
#pragma unroll
    for (int kd = 0; kd < 4; ++kd)
        qfrag[kd] = *reinterpret_cast<const bf16x8*>(
            &Q[qbase + (size_t)qrow_l * 2048 + hh * 128 + kd * 32 + lg * 8]);

    float mrow[4], lrow[4];
#pragma unroll
    for (int r = 0; r < 4; ++r) { mrow[r] = -INFINITY; lrow[r] = 0.f; }
    f32x4 accc[8];
#pragma unroll
    for (int nd = 0; nd < 8; ++nd) accc[nd] = (f32x4){0.f, 0.f, 0.f, 0.f};

    const float scale = 0.08838834764831845f;     // 1/sqrt(128)
    const int qm_base = qt * 64 + w * 16 + lg * 4; // masking rows for this lane
    const int ntiles = qt * 2 + 2;                 // causal: keys <= qt*64+63

    for (int t = 0; t < ntiles; ++t) {
        const int k0 = t * 32;
        __syncthreads();   // previous-iteration LDS reads complete
        // ---- stage K tile (32 x 128) row-major ----
#pragma unroll
        for (int i = 0; i < 2; ++i) {
            int f = tid + i * 256;                 // 512 chunks of 8
            int kk = f >> 4;
            int d8 = (f & 15) * 8;
            bf16x8 v = *reinterpret_cast<const bf16x8*>(
                &KV[kvbase + (size_t)(k0 + kk) * 1024 + g * 128 + d8]);
            *reinterpret_cast<bf16x8*>(&Klds[kk][d8]) = v;
        }
        // ---- stage V tile transposed: Vlds[d][k] ----
        {
            int dd = tid & 127;
            int hb = tid >> 7;
#pragma unroll
            for (int i = 0; i < 4; ++i) {
                int ks = hb * 4 + i * 8;
                const size_t base = kvbase + 512 + g * 128 + dd;
                unsigned short v0 = KV[base + (size_t)(k0 + ks + 0) * 1024];
                unsigned short v1 = KV[base + (size_t)(k0 + ks + 1) * 1024];
                unsigned short v2 = KV[base + (size_t)(k0 + ks + 2) * 1024];
                unsigned short v3 = KV[base + (size_t)(k0 + ks + 3) * 1024];
                bf16x4 pk = { (short)v0, (short)v1, (short)v2, (short)v3 };
                *reinterpret_cast<bf16x4*>(&Vlds[dd][ks]) = pk;
            }
        }
        __syncthreads();

        // ---- S = Q * K^T : D rows = q, cols = key ----
        f32x4 s[2];
        s[0] = (f32x4){0.f, 0.f, 0.f, 0.f};
        s[1] = (f32x4){0.f, 0.f, 0.f, 0.f};
#pragma unroll
        for (int nf = 0; nf < 2; ++nf) {
#pragma unroll
            for (int kd = 0; kd < 4; ++kd) {
                bf16x8 kf = *reinterpret_cast<const bf16x8*>(
                    &Klds[nf * 16 + l16][kd * 32 + lg * 8]);
                s[nf] = __builtin_amdgcn_mfma_f32_16x16x32_bf16(
                    qfrag[kd], kf, s[nf], 0, 0, 0);
            }
        }

        // ---- scale + causal mask + online softmax ----
#pragma unroll
        for (int r = 0; r < 4; ++r) {
            const int qrow = qm_base + r;
            float s0 = s[0][r] * scale;
            float s1 = s[1][r] * scale;
            if (k0 + l16 > qrow)      s0 = -INFINITY;
            if (k0 + 16 + l16 > qrow) s1 = -INFINITY;

            float mx = fmaxf(s0, s1);
#pragma unroll
            for (int mk = 1; mk < 16; mk <<= 1)
                mx = fmaxf(mx, __shfl_xor(mx, mk, 64));

            float mold = mrow[r];
            float mnew = fmaxf(mold, mx);
            float alpha = __expf(mold - mnew);
            float p0 = __expf(s0 - mnew);
            float p1 = __expf(s1 - mnew);
            float ps = p0 + p1;
#pragma unroll
            for (int mk = 1; mk < 16; mk <<= 1)
                ps += __shfl_xor(ps, mk, 64);
            lrow[r] = lrow[r] * alpha + ps;
            mrow[r] = mnew;
#pragma unroll
            for (int nd = 0; nd < 8; ++nd) accc[nd][r] *= alpha;

            Plds[w][lg * 4 + r][l16]      = f2bf(p0);
            Plds[w][lg * 4 + r][16 + l16] = f2bf(p1);
        }

        // ---- ctx += P * V  (P from per-wave LDS in A-fragment layout) ----
        bf16x8 pfrag = *reinterpret_cast<const bf16x8*>(&Plds[w][l16][lg * 8]);
#pragma unroll
        for (int nd = 0; nd < 8; ++nd) {
            bf16x8 vf = *reinterpret_cast<const bf16x8*>(
                &Vlds[nd * 16 + l16][lg * 8]);
            accc[nd] = __builtin_amdgcn_mfma_f32_16x16x32_bf16(
                pfrag, vf, accc[nd], 0, 0, 0);
        }
    }

    // ---- epilogue: ctx / l -> bf16 ----
#pragma unroll
    for (int r = 0; r < 4; ++r) {
        float inv = 1.0f / lrow[r];
        int row = qt * 64 + w * 16 + lg * 4 + r;
#pragma unroll
        for (int nd = 0; nd < 8; ++nd) {
            CTX[qbase + (size_t)row * 2048 + hh * 128 + nd * 16 + l16] =
                f2bf(accc[nd][r] * inv);
        }
    }
}

// ---------------------------------------------------------------------------
extern "C" void kernel_launch(void* const* d_in, const int* in_sizes, int n_in,
                              void* d_out, int out_size, void* d_ws, size_t ws_size,
                              hipStream_t stream)
{
    const float* x       = (const float*)d_in[0];
    const float* w_q     = (const float*)d_in[1];
    const float* w_kv    = (const float*)d_in[2];
    const float* w_dense = (const float*)d_in[3];
    float* out = (float*)d_out;

    const int Bc = 2, SQ = 2048, H = 2048;
    const int M = Bc * SQ;                         // 4096

    unsigned short* q_buf   = (unsigned short*)d_ws;            // 16 MB
    unsigned short* kv_buf  = q_buf  + (size_t)M * 2048;        //  8 MB
    unsigned short* ctx_buf = kv_buf + (size_t)M * 1024;        // 16 MB

    dim3 blk(256);
    // q = x * w_q   (4096 x 2048 x 2048) -> bf16
    gemm_kernel<false, true><<<dim3(2048 / 128, M / 128), blk, 0, stream>>>(
        (const void*)x, w_q, (void*)q_buf, M, 2048, H);
    // kv = x * w_kv (4096 x 1024 x 2048) -> bf16
    gemm_kernel<false, true><<<dim3(1024 / 128, M / 128), blk, 0, stream>>>(
        (const void*)x, w_kv, (void*)kv_buf, M, 1024, H);
    // attention -> ctx bf16
    attn_kernel<<<dim3(SQ / 64, 16, Bc), blk, 0, stream>>>(
        q_buf, kv_buf, ctx_buf, SQ);
    // out = ctx * w_dense (4096 x 2048 x 2048) -> fp32
    gemm_kernel<true, false><<<dim3(2048 / 128, M / 128), blk, 0, stream>>>(
        (const void*)ctx_buf, w_dense, (void*)out, M, 2048, H);
}

// Round 2
// 367.421 us; speedup vs baseline: 1.3196x; 1.3196x over previous
//
#include <hip/hip_runtime.h>
#include <hip/hip_bf16.h>

// ---------------------------------------------------------------------------
// Fused GQA attention block: out = dense( attn( x*Wq, x*Wkv ) )
// B=2, SQ=2048, HIDDEN=2048, HEADS=16, GROUPS=4, KVC=128, causal, scale=1/sqrt(128)
// ---------------------------------------------------------------------------

typedef __attribute__((ext_vector_type(4))) float f32x4;
typedef __attribute__((ext_vector_type(8))) short bf16x8;
typedef __attribute__((ext_vector_type(4))) short bf16x4;

__device__ __forceinline__ unsigned short f2bf(float f) {
    unsigned u = __builtin_bit_cast(unsigned, f);
    unsigned r = u + 0x7fffu + ((u >> 16) & 1u);   // round-to-nearest-even
    return (unsigned short)(r >> 16);
}

// async global->LDS, 16B per lane, dest = uniform base + lane*16
__device__ __forceinline__ void gl_lds16(const void* g, void* l) {
    __builtin_amdgcn_global_load_lds(
        (const __attribute__((address_space(1))) unsigned int*)g,
        (__attribute__((address_space(3))) unsigned int*)l, 16, 0, 0);
}

// ---------------------------------------------------------------------------
// GEMM: C(MxN) = A(MxK) * B(KxN).  (unchanged from R1 — verified working)
// ---------------------------------------------------------------------------
template<bool A_BF16, bool C_BF16>
__global__ __launch_bounds__(256)
void gemm_kernel(const void* __restrict__ Av, const float* __restrict__ B,
                 void* __restrict__ Cv, int M, int N, int K)
{
    __shared__ unsigned short Alds[128][40];   // [m][k]
    __shared__ unsigned short Blds[128][40];   // [n][k] (transposed)

    const int tid = threadIdx.x;
    const int lane = tid & 63;
    const int wid = tid >> 6;
    const int wr = wid >> 1, wc = wid & 1;
    const int m0 = blockIdx.y * 128;
    const int n0 = blockIdx.x * 128;
    const int l16 = lane & 15, lg = lane >> 4;

    f32x4 acc[4][4];
#pragma unroll
    for (int m = 0; m < 4; ++m)
#pragma unroll
        for (int n = 0; n < 4; ++n) acc[m][n] = (f32x4){0.f, 0.f, 0.f, 0.f};

    for (int kt = 0; kt < K; kt += 32) {
        if constexpr (A_BF16) {
            const unsigned short* A = (const unsigned short*)Av;
#pragma unroll
            for (int i = 0; i < 2; ++i) {
                int f = tid + i * 256;
                int row = f >> 2;
                int c8 = (f & 3) * 8;
                bf16x8 v = *reinterpret_cast<const bf16x8*>(
                    &A[(size_t)(m0 + row) * K + kt + c8]);
                *reinterpret_cast<bf16x8*>(&Alds[row][c8]) = v;
            }
        } else {
            const float* A = (const float*)Av;
#pragma unroll
            for (int i = 0; i < 4; ++i) {
                int f = tid + i * 256;
                int row = f >> 3;
                int c4 = (f & 7) * 4;
                float4 v = *reinterpret_cast<const float4*>(
                    &A[(size_t)(m0 + row) * K + kt + c4]);
                bf16x4 pk = { (short)f2bf(v.x), (short)f2bf(v.y),
                              (short)f2bf(v.z), (short)f2bf(v.w) };
                *reinterpret_cast<bf16x4*>(&Alds[row][c4]) = pk;
            }
        }
        {
            int nn = tid & 127;
            int hb = tid >> 7;
#pragma unroll
            for (int i = 0; i < 4; ++i) {
                int ks = hb * 4 + i * 8;
                float v0 = B[(size_t)(kt + ks + 0) * N + n0 + nn];
                float v1 = B[(size_t)(kt + ks + 1) * N + n0 + nn];
                float v2 = B[(size_t)(kt + ks + 2) * N + n0 + nn];
                float v3 = B[(size_t)(kt + ks + 3) * N + n0 + nn];
                bf16x4 pk = { (short)f2bf(v0), (short)f2bf(v1),
                              (short)f2bf(v2), (short)f2bf(v3) };
                *reinterpret_cast<bf16x4*>(&Blds[nn][ks]) = pk;
            }
        }
        __syncthreads();

        bf16x8 afrag[4], bfrag[4];
#pragma unroll
        for (int m = 0; m < 4; ++m)
            afrag[m] = *reinterpret_cast<const bf16x8*>(
                &Alds[wr * 64 + m * 16 + l16][lg * 8]);
#pragma unroll
        for (int n = 0; n < 4; ++n)
            bfrag[n] = *reinterpret_cast<const bf16x8*>(
                &Blds[wc * 64 + n * 16 + l16][lg * 8]);
#pragma unroll
        for (int m = 0; m < 4; ++m)
#pragma unroll
            for (int n = 0; n < 4; ++n)
                acc[m][n] = __builtin_amdgcn_mfma_f32_16x16x32_bf16(
                    afrag[m], bfrag[n], acc[m][n], 0, 0, 0);
        __syncthreads();
    }

#pragma unroll
    for (int m = 0; m < 4; ++m) {
#pragma unroll
        for (int n = 0; n < 4; ++n) {
#pragma unroll
            for (int r = 0; r < 4; ++r) {
                int row = m0 + wr * 64 + m * 16 + lg * 4 + r;
                int col = n0 + wc * 64 + n * 16 + l16;
                float val = acc[m][n][r];
                if constexpr (C_BF16)
                    ((unsigned short*)Cv)[(size_t)row * N + col] = f2bf(val);
                else
                    ((float*)Cv)[(size_t)row * N + col] = val;
            }
        }
    }
}

// ---------------------------------------------------------------------------
// V transpose: kv_buf v-part [b][s][g*128+d] -> vt [b*4+g][d][s]   (4 MB)
// ---------------------------------------------------------------------------
__global__ __launch_bounds__(256)
void vtrans_kernel(const unsigned short* __restrict__ kv,
                   unsigned short* __restrict__ vt)
{
    __shared__ unsigned short T[64][140];      // pad 140: write-out ~8-way max
    const int bg = blockIdx.y;                 // b*4+g
    const int b = bg >> 2, g = bg & 3;
    const int s0 = blockIdx.x * 64;
    const int tid = threadIdx.x;

#pragma unroll
    for (int i = 0; i < 4; ++i) {
        int f = tid + i * 256;
        int sl = f >> 4;
        int d0 = (f & 15) * 8;
        bf16x8 v = *reinterpret_cast<const bf16x8*>(
            &kv[(size_t)(b * 2048 + s0 + sl) * 1024 + 512 + g * 128 + d0]);
        bf16x4 lo = { v[0], v[1], v[2], v[3] };
        bf16x4 hi = { v[4], v[5], v[6], v[7] };
        *reinterpret_cast<bf16x4*>(&T[sl][d0])     = lo;
        *reinterpret_cast<bf16x4*>(&T[sl][d0 + 4]) = hi;
    }
    __syncthreads();
#pragma unroll
    for (int i = 0; i < 4; ++i) {
        int f = tid + i * 256;
        int d = f >> 3;
        int s8 = (f & 7) * 8;
        bf16x8 o;
#pragma unroll
        for (int j = 0; j < 8; ++j) o[j] = T[s8 + j][d];
        *reinterpret_cast<bf16x8*>(
            &vt[(size_t)(bg * 128 + d) * 2048 + s0 + s8]) = o;
    }
}

// ---------------------------------------------------------------------------
// Flash attention v2. Block = one KV group: 4 waves = 4 heads, 32 q-rows each.
// KBLK=64. K [64][128] / V^T [128][64] in LDS, XOR-swizzled (byte ^=
// (row&7)<<4) via pre-swizzled global source + global_load_lds width 16.
// exp2-domain online softmax, defer-max (THR=8), diag-only masking.
// Grid: 512 1-D blocks; bid&7 = (g + 4b) pins each group to one XCD; the
// qt order interleaves long/short for load balance.
// ---------------------------------------------------------------------------
__global__ __launch_bounds__(256, 2)
void attn_kernel(const unsigned short* __restrict__ Q,   // [b][s][h*128+d]
                 const unsigned short* __restrict__ KV,  // [b][s][1024] (k at g*128)
                 const unsigned short* __restrict__ VT,  // [b*4+g][d][s]
                 unsigned short* __restrict__ CTX)       // [b][s][h*128+d]
{
    constexpr int SQ = 2048;
    __shared__ __align__(16) unsigned short Klds[64 * 128];
    __shared__ __align__(16) unsigned short Vlds[128 * 64];
    __shared__ __align__(16) unsigned short Plds[4][32][72];

    const int tid = threadIdx.x;
    const int lane = tid & 63;
    const int w = tid >> 6;
    const int l16 = lane & 15, lg = lane >> 4;

    const int bid = blockIdx.x;
    const int gb = bid & 7;                     // XCD pin
    const int g = gb & 3, b = gb >> 2;
    const int qo = bid >> 3;
    const int qt = (qo & 1) ? (qo >> 1) : (63 - (qo >> 1));  // long first
    const int hh = g * 4 + w;                   // head for this wave

    const size_t qbase = (size_t)b * SQ * 2048;

    // hoist Q fragments: rows qt*32 + m*16 + l16, 4 K-steps over D=128
    bf16x8 qfrag[2][4];
#pragma unroll
    for (int m = 0; m < 2; ++m)
#pragma unroll
        for (int kd = 0; kd < 4; ++kd)
            qfrag[m][kd] = *reinterpret_cast<const bf16x8*>(
                &Q[qbase + (size_t)(qt * 32 + m * 16 + l16) * 2048 +
                   hh * 128 + kd * 32 + lg * 8]);

    float m2[2][4], lsum[2][4];
#pragma unroll
    for (int m = 0; m < 2; ++m)
#pragma unroll
        for (int r = 0; r < 4; ++r) { m2[m][r] = -INFINITY; lsum[m][r] = 0.f; }
    f32x4 acc[2][8];
#pragma unroll
    for (int m = 0; m < 2; ++m)
#pragma unroll
        for (int nd = 0; nd < 8; ++nd) acc[m][nd] = (f32x4){0.f,0.f,0.f,0.f};

    const float c2 = 0.12751879523209208f;      // (1/sqrt(128)) * log2(e)
    const int ntiles = qt / 2 + 1;

    const char* KVb = (const char*)KV + (size_t)b * SQ * 2048;  // bytes
    const char* VTb = (const char*)VT;

    for (int t = 0; t < ntiles; ++t) {
        const int k0 = t * 64;
        // ---- stage K tile (64x128), pre-swizzled source ----
#pragma unroll
        for (int i = 0; i < 4; ++i) {
            int row = w * 16 + i * 4 + (lane >> 4);
            int scol = ((lane & 15) * 16) ^ ((row & 7) << 4);
            gl_lds16(KVb + (size_t)(k0 + row) * 2048 + g * 256 + scol,
                     (char*)Klds + w * 4096 + i * 1024);
        }
        // ---- stage V^T tile (128x64), pre-swizzled source ----
#pragma unroll
        for (int i = 0; i < 4; ++i) {
            int row = w * 32 + i * 8 + (lane >> 3);
            int scol = ((lane & 7) * 16) ^ ((row & 7) << 4);
            gl_lds16(VTb + ((size_t)(gb * 128 + row) * 2048 + k0) * 2 + scol,
                     (char*)Vlds + w * 4096 + i * 1024);
        }
        __syncthreads();   // drains vmcnt, data in LDS

        // ---- S = Q K^T ----
        f32x4 s[2][4];
#pragma unroll
        for (int m = 0; m < 2; ++m)
#pragma unroll
            for (int nf = 0; nf < 4; ++nf) s[m][nf] = (f32x4){0.f,0.f,0.f,0.f};
#pragma unroll
        for (int nf = 0; nf < 4; ++nf) {
            int row = nf * 16 + l16;
#pragma unroll
            for (int kd = 0; kd < 4; ++kd) {
                bf16x8 kf = *reinterpret_cast<const bf16x8*>(
                    (const char*)Klds + row * 256 +
                    ((kd * 64 + lg * 16) ^ ((row & 7) << 4)));
                s[0][nf] = __builtin_amdgcn_mfma_f32_16x16x32_bf16(
                    qfrag[0][kd], kf, s[0][nf], 0, 0, 0);
                s[1][nf] = __builtin_amdgcn_mfma_f32_16x16x32_bf16(
                    qfrag[1][kd], kf, s[1][nf], 0, 0, 0);
            }
        }

        // ---- online softmax (exp2 domain), mask only on diagonal tile ----
        const bool diag = (t == ntiles - 1);
#pragma unroll
        for (int m = 0; m < 2; ++m) {
#pragma unroll
            for (int r = 0; r < 4; ++r) {
                float cs0 = s[m][0][r] * c2;
                float cs1 = s[m][1][r] * c2;
                float cs2 = s[m][2][r] * c2;
                float cs3 = s[m][3][r] * c2;
                if (diag) {
                    const int qrow = qt * 32 + m * 16 + lg * 4 + r;
                    if (k0 +      l16 > qrow) cs0 = -INFINITY;
                    if (k0 + 16 + l16 > qrow) cs1 = -INFINITY;
                    if (k0 + 32 + l16 > qrow) cs2 = -INFINITY;
                    if (k0 + 48 + l16 > qrow) cs3 = -INFINITY;
                }
                float mx = fmaxf(fmaxf(cs0, cs1), fmaxf(cs2, cs3));
#pragma unroll
                for (int mk = 1; mk < 16; mk <<= 1)
                    mx = fmaxf(mx, __shfl_xor(mx, mk, 64));
                float mo = m2[m][r];
                if (__any(mx > mo + 8.0f)) {     // defer-max rescale
                    float mn = fmaxf(mo, mx);
                    float al = exp2f(mo - mn);
                    m2[m][r] = mn;
                    lsum[m][r] *= al;
#pragma unroll
                    for (int nd = 0; nd < 8; ++nd) acc[m][nd][r] *= al;
                }
                float mm = m2[m][r];
                float p0 = exp2f(cs0 - mm);
                float p1 = exp2f(cs1 - mm);
                float p2 = exp2f(cs2 - mm);
                float p3 = exp2f(cs3 - mm);
                float ps = (p0 + p1) + (p2 + p3);
#pragma unroll
                for (int mk = 1; mk < 16; mk <<= 1)
                    ps += __shfl_xor(ps, mk, 64);
                lsum[m][r] += ps;
                const int qrl = m * 16 + lg * 4 + r;
                Plds[w][qrl][ 0 + l16] = f2bf(p0);
                Plds[w][qrl][16 + l16] = f2bf(p1);
                Plds[w][qrl][32 + l16] = f2bf(p2);
                Plds[w][qrl][48 + l16] = f2bf(p3);
            }
        }

        // ---- ctx += P V ----
#pragma unroll
        for (int kc = 0; kc < 2; ++kc) {
            bf16x8 pa = *reinterpret_cast<const bf16x8*>(
                &Plds[w][ 0 + l16][kc * 32 + lg * 8]);
            bf16x8 pb = *reinterpret_cast<const bf16x8*>(
                &Plds[w][16 + l16][kc * 32 + lg * 8]);
#pragma unroll
            for (int nd = 0; nd < 8; ++nd) {
                int row = nd * 16 + l16;
                bf16x8 vf = *reinterpret_cast<const bf16x8*>(
                    (const char*)Vlds + row * 128 +
                    ((kc * 64 + lg * 16) ^ ((row & 7) << 4)));
                acc[0][nd] = __builtin_amdgcn_mfma_f32_16x16x32_bf16(
                    pa, vf, acc[0][nd], 0, 0, 0);
                acc[1][nd] = __builtin_amdgcn_mfma_f32_16x16x32_bf16(
                    pb, vf, acc[1][nd], 0, 0, 0);
            }
        }
        __syncthreads();   // protect K/V LDS before next tile's staging
    }

    // ---- epilogue ----
#pragma unroll
    for (int m = 0; m < 2; ++m) {
#pragma unroll
        for (int r = 0; r < 4; ++r) {
            float inv = 1.0f / lsum[m][r];
            int row = qt * 32 + m * 16 + lg * 4 + r;
#pragma unroll
            for (int nd = 0; nd < 8; ++nd)
                CTX[qbase + (size_t)row * 2048 + hh * 128 + nd * 16 + l16] =
                    f2bf(acc[m][nd][r] * inv);
        }
    }
}

// ---------------------------------------------------------------------------
extern "C" void kernel_launch(void* const* d_in, const int* in_sizes, int n_in,
                              void* d_out, int out_size, void* d_ws, size_t ws_size,
                              hipStream_t stream)
{
    const float* x       = (const float*)d_in[0];
    const float* w_q     = (const float*)d_in[1];
    const float* w_kv    = (const float*)d_in[2];
    const float* w_dense = (const float*)d_in[3];
    float* out = (float*)d_out;

    const int Bc = 2, SQ = 2048, H = 2048;
    const int M = Bc * SQ;                         // 4096

    unsigned short* q_buf   = (unsigned short*)d_ws;            // 16 MB
    unsigned short* kv_buf  = q_buf  + (size_t)M * 2048;        //  8 MB
    unsigned short* ctx_buf = kv_buf + (size_t)M * 1024;        // 16 MB
    // vt (4 MB) lives in d_out: written after kv GEMM, consumed by attention,
    // then fully overwritten by the final dense GEMM. Deterministic each call.
    unsigned short* vt_buf  = (unsigned short*)d_out;

    dim3 blk(256);
    gemm_kernel<false, true><<<dim3(2048 / 128, M / 128), blk, 0, stream>>>(
        (const void*)x, w_q, (void*)q_buf, M, 2048, H);
    gemm_kernel<false, true><<<dim3(1024 / 128, M / 128), blk, 0, stream>>>(
        (const void*)x, w_kv, (void*)kv_buf, M, 1024, H);
    vtrans_kernel<<<dim3(32, 8), blk, 0, stream>>>(kv_buf, vt_buf);
    attn_kernel<<<dim3(512), blk, 0, stream>>>(q_buf, kv_buf, vt_buf, ctx_buf);
    gemm_kernel<true, false><<<dim3(2048 / 128, M / 128), blk, 0, stream>>>(
        (const void*)ctx_buf, w_dense, (void*)out, M, 2048, H);
}

// Round 4
// 304.094 us; speedup vs baseline: 1.5945x; 1.2082x over previous
//
#include <hip/hip_runtime.h>
#include <hip/hip_bf16.h>

// ---------------------------------------------------------------------------
// Fused GQA attention block: out = dense( attn( x*Wq, x*Wkv ) )
// B=2, SQ=2048, HIDDEN=2048, HEADS=16, GROUPS=4, KVC=128, causal, scale=1/sqrt(128)
// R4: R3 with the wtrans write-phase OOB fixed (i<2, not i<4).
// ---------------------------------------------------------------------------

typedef __attribute__((ext_vector_type(4))) float f32x4;
typedef __attribute__((ext_vector_type(8))) short bf16x8;
typedef __attribute__((ext_vector_type(4))) short bf16x4;

__device__ __forceinline__ unsigned short f2bf(float f) {
    unsigned u = __builtin_bit_cast(unsigned, f);
    unsigned r = u + 0x7fffu + ((u >> 16) & 1u);   // round-to-nearest-even
    return (unsigned short)(r >> 16);
}

// async global->LDS, 16B/lane; LDS dest = wave-uniform base + lane*16
__device__ __forceinline__ void gl_lds16(const void* g, void* l) {
    __builtin_amdgcn_global_load_lds(
        (const __attribute__((address_space(1))) unsigned int*)g,
        (__attribute__((address_space(3))) unsigned int*)l, 16, 0, 0);
}

// ---------------------------------------------------------------------------
// Weight transpose+convert: in fp32 [K][N] -> out bf16 [N][K].  64x64 tiles.
// ---------------------------------------------------------------------------
__global__ __launch_bounds__(256)
void wtrans_kernel(const float* __restrict__ in, unsigned short* __restrict__ out,
                   int K, int N)
{
    __shared__ unsigned short T[64][72];
    const int n0 = blockIdx.x * 64, k0 = blockIdx.y * 64;
    const int tid = threadIdx.x;
#pragma unroll
    for (int i = 0; i < 4; ++i) {
        int f = tid + i * 256;            // 1024 float4 chunks (64 rows x 16)
        int r = f >> 4;                   // k row in tile
        int c4 = (f & 15) * 4;            // n col
        float4 v = *reinterpret_cast<const float4*>(&in[(size_t)(k0 + r) * N + n0 + c4]);
        bf16x4 pk = { (short)f2bf(v.x), (short)f2bf(v.y),
                      (short)f2bf(v.z), (short)f2bf(v.w) };
        *reinterpret_cast<bf16x4*>(&T[r][c4]) = pk;
    }
    __syncthreads();
#pragma unroll
    for (int i = 0; i < 2; ++i) {         // FIX: 512 bf16x8 chunks (64 rows x 8)
        int f = tid + i * 256;
        int nn = f >> 3;                  // n row (out), [0,64)
        int s8 = (f & 7) * 8;             // k col
        bf16x8 o;
#pragma unroll
        for (int j = 0; j < 8; ++j) o[j] = T[s8 + j][nn];
        *reinterpret_cast<bf16x8*>(&out[(size_t)(n0 + nn) * K + k0 + s8]) = o;
    }
}

// ---------------------------------------------------------------------------
// GEMM: C(MxN) = A(MxK) * BT(NxK)^T.  BT is bf16 row-major [N][K].
// m97 structure: 128x128 tile, BK=64, 4 waves (2x2), 4x4 16x16x32 frags/wave.
// LDS [128][64] bf16 linear, T2 XOR swizzle (byte ^= (row&7)<<4) applied via
// pre-swizzled global_load_lds source (bf16 A / B) or swizzled ds_write (fp32
// A, fused f32->bf16 convert).  Reads deswizzle with the same XOR.
// ---------------------------------------------------------------------------
template<bool A_BF16, bool SPLIT_QKV>
__global__ __launch_bounds__(256)
void gemm_bt_kernel(const void* __restrict__ Av, const unsigned short* __restrict__ BT,
                    void* __restrict__ C0v, void* __restrict__ C1v,
                    int M, int N, int K)
{
    __shared__ __align__(16) unsigned short Alds[128 * 64];
    __shared__ __align__(16) unsigned short Blds[128 * 64];

    const int tid = threadIdx.x;
    const int lane = tid & 63;
    const int wid = tid >> 6;
    const int wr = wid >> 1, wc = wid & 1;
    const int m0 = blockIdx.y * 128;
    const int n0 = blockIdx.x * 128;
    const int l16 = lane & 15, lg = lane >> 4;

    f32x4 acc[4][4];
#pragma unroll
    for (int m = 0; m < 4; ++m)
#pragma unroll
        for (int n = 0; n < 4; ++n) acc[m][n] = (f32x4){0.f, 0.f, 0.f, 0.f};

    for (int kt = 0; kt < K; kt += 64) {
        // ---- stage A tile (128 rows x 64 k) ----
        if constexpr (A_BF16) {
            const unsigned short* A = (const unsigned short*)Av;
#pragma unroll
            for (int i = 0; i < 4; ++i) {
                int row = i * 32 + (tid >> 3);
                int cb = ((tid & 7) * 16) ^ ((row & 7) << 4);
                gl_lds16((const char*)A + ((size_t)(m0 + row) * K + kt) * 2 + cb,
                         (char*)Alds + i * 4096 + wid * 1024);
            }
        } else {
            const float* A = (const float*)Av;
#pragma unroll
            for (int i = 0; i < 8; ++i) {
                int f = tid + i * 256;            // 2048 float4 chunks
                int row = f >> 4;
                int c4 = (f & 15) * 4;
                float4 v = *reinterpret_cast<const float4*>(
                    &A[(size_t)(m0 + row) * K + kt + c4]);
                bf16x4 pk = { (short)f2bf(v.x), (short)f2bf(v.y),
                              (short)f2bf(v.z), (short)f2bf(v.w) };
                int cb = (c4 * 2) ^ ((row & 7) << 4);
                *reinterpret_cast<bf16x4*>((char*)Alds + row * 128 + cb) = pk;
            }
        }
        // ---- stage B tile (128 n-rows x 64 k) via global_load_lds ----
#pragma unroll
        for (int i = 0; i < 4; ++i) {
            int row = i * 32 + (tid >> 3);
            int cb = ((tid & 7) * 16) ^ ((row & 7) << 4);
            gl_lds16((const char*)BT + ((size_t)(n0 + row) * K + kt) * 2 + cb,
                     (char*)Blds + i * 4096 + wid * 1024);
        }
        __syncthreads();

        bf16x8 af[2][4], bf[2][4];
#pragma unroll
        for (int kd = 0; kd < 2; ++kd) {
#pragma unroll
            for (int m = 0; m < 4; ++m) {
                int row = wr * 64 + m * 16 + l16;
                af[kd][m] = *reinterpret_cast<const bf16x8*>(
                    (const char*)Alds + row * 128 +
                    ((kd * 64 + lg * 16) ^ ((row & 7) << 4)));
            }
#pragma unroll
            for (int n = 0; n < 4; ++n) {
                int row = wc * 64 + n * 16 + l16;
                bf[kd][n] = *reinterpret_cast<const bf16x8*>(
                    (const char*)Blds + row * 128 +
                    ((kd * 64 + lg * 16) ^ ((row & 7) << 4)));
            }
        }
        __builtin_amdgcn_s_setprio(1);
#pragma unroll
        for (int kd = 0; kd < 2; ++kd)
#pragma unroll
            for (int m = 0; m < 4; ++m)
#pragma unroll
                for (int n = 0; n < 4; ++n)
                    acc[m][n] = __builtin_amdgcn_mfma_f32_16x16x32_bf16(
                        af[kd][m], bf[kd][n], acc[m][n], 0, 0, 0);
        __builtin_amdgcn_s_setprio(0);
        __syncthreads();
    }

    // ---- epilogue: C/D layout col = lane&15, row = (lane>>4)*4 + reg ----
#pragma unroll
    for (int m = 0; m < 4; ++m) {
#pragma unroll
        for (int n = 0; n < 4; ++n) {
#pragma unroll
            for (int r = 0; r < 4; ++r) {
                int row = m0 + wr * 64 + m * 16 + lg * 4 + r;
                int col = n0 + wc * 64 + n * 16 + l16;
                float val = acc[m][n][r];
                if constexpr (SPLIT_QKV) {
                    if (n0 < 2048)
                        ((unsigned short*)C0v)[(size_t)row * 2048 + col] = f2bf(val);
                    else
                        ((unsigned short*)C1v)[(size_t)row * 1024 + (col - 2048)] = f2bf(val);
                } else {
                    ((float*)C0v)[(size_t)row * N + col] = val;
                }
            }
        }
    }
}

// ---------------------------------------------------------------------------
// V transpose: kv_buf v-part [b][s][512 + g*128 + d] -> vt [b*4+g][d][s]
// ---------------------------------------------------------------------------
__global__ __launch_bounds__(256)
void vtrans_kernel(const unsigned short* __restrict__ kv,
                   unsigned short* __restrict__ vt)
{
    __shared__ unsigned short T[64][140];
    const int bg = blockIdx.y;                 // b*4+g
    const int b = bg >> 2, g = bg & 3;
    const int s0 = blockIdx.x * 64;
    const int tid = threadIdx.x;

#pragma unroll
    for (int i = 0; i < 4; ++i) {
        int f = tid + i * 256;
        int sl = f >> 4;
        int d0 = (f & 15) * 8;
        bf16x8 v = *reinterpret_cast<const bf16x8*>(
            &kv[(size_t)(b * 2048 + s0 + sl) * 1024 + 512 + g * 128 + d0]);
        bf16x4 lo = { v[0], v[1], v[2], v[3] };
        bf16x4 hi = { v[4], v[5], v[6], v[7] };
        *reinterpret_cast<bf16x4*>(&T[sl][d0])     = lo;
        *reinterpret_cast<bf16x4*>(&T[sl][d0 + 4]) = hi;
    }
    __syncthreads();
#pragma unroll
    for (int i = 0; i < 4; ++i) {
        int f = tid + i * 256;
        int d = f >> 3;
        int s8 = (f & 7) * 8;
        bf16x8 o;
#pragma unroll
        for (int j = 0; j < 8; ++j) o[j] = T[s8 + j][d];
        *reinterpret_cast<bf16x8*>(
            &vt[(size_t)(bg * 128 + d) * 2048 + s0 + s8]) = o;
    }
}

// ---------------------------------------------------------------------------
// Flash attention v3.  Block = one KV group: 4 waves = 4 heads, 32 q-rows each.
// KBLK=64; K/V^T LDS XOR-swizzled via pre-swizzled global_load_lds source.
// Balanced causal mapping: bid i and i+256 land on the same CU (round-robin),
// qt(i) + qt(i+256) = 63 -> every CU gets ~33 key-tiles of work.
// ---------------------------------------------------------------------------
__global__ __launch_bounds__(256, 2)
void attn_kernel(const unsigned short* __restrict__ Q,   // [b][s][h*128+d]
                 const unsigned short* __restrict__ KV,  // [b][s][1024] (k at g*128)
                 const unsigned short* __restrict__ VT,  // [b*4+g][d][s]
                 unsigned short* __restrict__ CTX)       // [b][s][h*128+d]
{
    constexpr int SQ = 2048;
    __shared__ __align__(16) unsigned short Klds[64 * 128];
    __shared__ __align__(16) unsigned short Vlds[128 * 64];
    __shared__ __align__(16) unsigned short Plds[4][32][72];

    const int tid = threadIdx.x;
    const int lane = tid & 63;
    const int w = tid >> 6;
    const int l16 = lane & 15, lg = lane >> 4;

    const int bid = blockIdx.x;
    const int gb = bid & 7;                     // XCD pin
    const int g = gb & 3, b = gb >> 2;
    const int qo = bid >> 3;
    const int qt = (qo < 32) ? (63 - qo) : (qo - 32);   // balanced pairing
    const int hh = g * 4 + w;                   // head for this wave

    const size_t qbase = (size_t)b * SQ * 2048;

    bf16x8 qfrag[2][4];
#pragma unroll
    for (int m = 0; m < 2; ++m)
#pragma unroll
        for (int kd = 0; kd < 4; ++kd)
            qfrag[m][kd] = *reinterpret_cast<const bf16x8*>(
                &Q[qbase + (size_t)(qt * 32 + m * 16 + l16) * 2048 +
                   hh * 128 + kd * 32 + lg * 8]);

    float m2[2][4], lsum[2][4];
#pragma unroll
    for (int m = 0; m < 2; ++m)
#pragma unroll
        for (int r = 0; r < 4; ++r) { m2[m][r] = -INFINITY; lsum[m][r] = 0.f; }
    f32x4 acc[2][8];
#pragma unroll
    for (int m = 0; m < 2; ++m)
#pragma unroll
        for (int nd = 0; nd < 8; ++nd) acc[m][nd] = (f32x4){0.f,0.f,0.f,0.f};

    const float c2 = 0.12751879523209208f;      // (1/sqrt(128)) * log2(e)
    const int ntiles = qt / 2 + 1;

    const char* KVb = (const char*)KV + (size_t)b * SQ * 2048;  // bytes
    const char* VTb = (const char*)VT;

    for (int t = 0; t < ntiles; ++t) {
        const int k0 = t * 64;
#pragma unroll
        for (int i = 0; i < 4; ++i) {
            int row = w * 16 + i * 4 + (lane >> 4);
            int scol = ((lane & 15) * 16) ^ ((row & 7) << 4);
            gl_lds16(KVb + (size_t)(k0 + row) * 2048 + g * 256 + scol,
                     (char*)Klds + w * 4096 + i * 1024);
        }
#pragma unroll
        for (int i = 0; i < 4; ++i) {
            int row = w * 32 + i * 8 + (lane >> 3);
            int scol = ((lane & 7) * 16) ^ ((row & 7) << 4);
            gl_lds16(VTb + ((size_t)(gb * 128 + row) * 2048 + k0) * 2 + scol,
                     (char*)Vlds + w * 4096 + i * 1024);
        }
        __syncthreads();   // drains vmcnt, data in LDS

        // ---- S = Q K^T ----
        f32x4 s[2][4];
#pragma unroll
        for (int m = 0; m < 2; ++m)
#pragma unroll
            for (int nf = 0; nf < 4; ++nf) s[m][nf] = (f32x4){0.f,0.f,0.f,0.f};
        __builtin_amdgcn_s_setprio(1);
#pragma unroll
        for (int nf = 0; nf < 4; ++nf) {
            int row = nf * 16 + l16;
#pragma unroll
            for (int kd = 0; kd < 4; ++kd) {
                bf16x8 kf = *reinterpret_cast<const bf16x8*>(
                    (const char*)Klds + row * 256 +
                    ((kd * 64 + lg * 16) ^ ((row & 7) << 4)));
                s[0][nf] = __builtin_amdgcn_mfma_f32_16x16x32_bf16(
                    qfrag[0][kd], kf, s[0][nf], 0, 0, 0);
                s[1][nf] = __builtin_amdgcn_mfma_f32_16x16x32_bf16(
                    qfrag[1][kd], kf, s[1][nf], 0, 0, 0);
            }
        }
        __builtin_amdgcn_s_setprio(0);

        // ---- online softmax (exp2 domain), mask only on diagonal tile ----
        const bool diag = (t == ntiles - 1);
#pragma unroll
        for (int m = 0; m < 2; ++m) {
#pragma unroll
            for (int r = 0; r < 4; ++r) {
                float cs0 = s[m][0][r] * c2;
                float cs1 = s[m][1][r] * c2;
                float cs2 = s[m][2][r] * c2;
                float cs3 = s[m][3][r] * c2;
                if (diag) {
                    const int qrow = qt * 32 + m * 16 + lg * 4 + r;
                    if (k0 +      l16 > qrow) cs0 = -INFINITY;
                    if (k0 + 16 + l16 > qrow) cs1 = -INFINITY;
                    if (k0 + 32 + l16 > qrow) cs2 = -INFINITY;
                    if (k0 + 48 + l16 > qrow) cs3 = -INFINITY;
                }
                float mx = fmaxf(fmaxf(cs0, cs1), fmaxf(cs2, cs3));
#pragma unroll
                for (int mk = 1; mk < 16; mk <<= 1)
                    mx = fmaxf(mx, __shfl_xor(mx, mk, 64));
                float mo = m2[m][r];
                if (__any(mx > mo + 8.0f)) {     // defer-max rescale
                    float mn = fmaxf(mo, mx);
                    float al = exp2f(mo - mn);
                    m2[m][r] = mn;
                    lsum[m][r] *= al;
#pragma unroll
                    for (int nd = 0; nd < 8; ++nd) acc[m][nd][r] *= al;
                }
                float mm = m2[m][r];
                float p0 = exp2f(cs0 - mm);
                float p1 = exp2f(cs1 - mm);
                float p2 = exp2f(cs2 - mm);
                float p3 = exp2f(cs3 - mm);
                float ps = (p0 + p1) + (p2 + p3);
#pragma unroll
                for (int mk = 1; mk < 16; mk <<= 1)
                    ps += __shfl_xor(ps, mk, 64);
                lsum[m][r] += ps;
                const int qrl = m * 16 + lg * 4 + r;
                Plds[w][qrl][ 0 + l16] = f2bf(p0);
                Plds[w][qrl][16 + l16] = f2bf(p1);
                Plds[w][qrl][32 + l16] = f2bf(p2);
                Plds[w][qrl][48 + l16] = f2bf(p3);
            }
        }

        // ---- ctx += P V ----
        __builtin_amdgcn_s_setprio(1);
#pragma unroll
        for (int kc = 0; kc < 2; ++kc) {
            bf16x8 pa = *reinterpret_cast<const bf16x8*>(
                &Plds[w][ 0 + l16][kc * 32 + lg * 8]);
            bf16x8 pb = *reinterpret_cast<const bf16x8*>(
                &Plds[w][16 + l16][kc * 32 + lg * 8]);
#pragma unroll
            for (int nd = 0; nd < 8; ++nd) {
                int row = nd * 16 + l16;
                bf16x8 vf = *reinterpret_cast<const bf16x8*>(
                    (const char*)Vlds + row * 128 +
                    ((kc * 64 + lg * 16) ^ ((row & 7) << 4)));
                acc[0][nd] = __builtin_amdgcn_mfma_f32_16x16x32_bf16(
                    pa, vf, acc[0][nd], 0, 0, 0);
                acc[1][nd] = __builtin_amdgcn_mfma_f32_16x16x32_bf16(
                    pb, vf, acc[1][nd], 0, 0, 0);
            }
        }
        __builtin_amdgcn_s_setprio(0);
        __syncthreads();   // protect K/V LDS before next tile's staging
    }

    // ---- epilogue ----
#pragma unroll
    for (int m = 0; m < 2; ++m) {
#pragma unroll
        for (int r = 0; r < 4; ++r) {
            float inv = 1.0f / lsum[m][r];
            int row = qt * 32 + m * 16 + lg * 4 + r;
#pragma unroll
            for (int nd = 0; nd < 8; ++nd)
                CTX[qbase + (size_t)row * 2048 + hh * 128 + nd * 16 + l16] =
                    f2bf(acc[m][nd][r] * inv);
        }
    }
}

// ---------------------------------------------------------------------------
extern "C" void kernel_launch(void* const* d_in, const int* in_sizes, int n_in,
                              void* d_out, int out_size, void* d_ws, size_t ws_size,
                              hipStream_t stream)
{
    const float* x       = (const float*)d_in[0];
    const float* w_q     = (const float*)d_in[1];
    const float* w_kv    = (const float*)d_in[2];
    const float* w_dense = (const float*)d_in[3];
    float* out = (float*)d_out;

    const int Bc = 2, SQ = 2048, H = 2048;
    const int M = Bc * SQ;                         // 4096

    // ws layout (36 MB total; 40 MB proven available):
    //   kv_buf  8 MB @ 0
    //   ctx_buf 16 MB @ 8 MB
    //   wqT     8 MB @ 24 MB  (later reused for wdT)
    //   wkvT    4 MB @ 32 MB  (contiguous after wqT -> combined BT [3072][2048])
    char* ws = (char*)d_ws;
    unsigned short* kv_buf  = (unsigned short*)(ws);
    unsigned short* ctx_buf = (unsigned short*)(ws + (8u << 20));
    unsigned short* wqT     = (unsigned short*)(ws + (24u << 20));
    unsigned short* wkvT    = (unsigned short*)(ws + (32u << 20));
    unsigned short* wdT     = wqT;                 // reuse after qkv GEMM
    // d_out (32 MB fp32) temporarily hosts q_buf (16 MB bf16) + vt (4 MB);
    // both are consumed by attn, then the dense GEMM overwrites all of d_out.
    unsigned short* q_buf = (unsigned short*)d_out;
    unsigned short* vt_buf = (unsigned short*)((char*)d_out + (16u << 20));

    dim3 blk(256);
    // weights -> bf16 [N][K]
    wtrans_kernel<<<dim3(32, 32), blk, 0, stream>>>(w_q, wqT, H, 2048);
    wtrans_kernel<<<dim3(16, 32), blk, 0, stream>>>(w_kv, wkvT, H, 1024);
    // fused q+kv projection: A = x fp32, BT = [wqT;wkvT] (3072 x 2048)
    gemm_bt_kernel<false, true><<<dim3(24, 32), blk, 0, stream>>>(
        (const void*)x, wqT, (void*)q_buf, (void*)kv_buf, M, 3072, H);
    // dense weight transpose (overwrites wqT region; stream-ordered after qkv GEMM)
    wtrans_kernel<<<dim3(32, 32), blk, 0, stream>>>(w_dense, wdT, 2048, 2048);
    vtrans_kernel<<<dim3(32, 8), blk, 0, stream>>>(kv_buf, vt_buf);
    attn_kernel<<<dim3(512), blk, 0, stream>>>(q_buf, kv_buf, vt_buf, ctx_buf);
    // out = ctx * w_dense
    gemm_bt_kernel<true, false><<<dim3(16, 32), blk, 0, stream>>>(
        (const void*)ctx_buf, wdT, (void*)out, nullptr, M, 2048, 2048);
}